// Round 4
// baseline (1034.004 us; speedup 1.0000x reference)
//
#include <hip/hip_runtime.h>

// NystromAttention on MI355X. fp32 I/O. bf16 MFMA for attention matmuls;
// Newton inverse fused into ONE kernel (48 blocks, one per bh) using bf16x3
// split-precision MFMA (~1e-5 relative per matmul).

typedef unsigned int uint_t;
typedef unsigned short ushort_t;
typedef short s16x8 __attribute__((ext_vector_type(8)));
typedef float f32x4 __attribute__((ext_vector_type(4)));

#define NB 4
#define NH 12
#define BH 48
#define SQ 4096
#define HD 64
#define NL 128
#define SEG 32
#define SCALE 0.35355339059327379f
#define NEGBIG 1.0e9f

__device__ __forceinline__ ushort_t f2bf(float f) {
    uint_t u = __float_as_uint(f);
    u += 0x7FFFu + ((u >> 16) & 1u);   // RNE
    return (ushort_t)(u >> 16);
}
__device__ __forceinline__ uint_t pack2(float a, float b) {
    return (uint_t)f2bf(a) | ((uint_t)f2bf(b) << 16);
}
__device__ __forceinline__ s16x8 ld_frag(const ushort_t* p) {
    return __builtin_bit_cast(s16x8, *(const uint4*)p);
}
#define MFMA16(a, b, c) __builtin_amdgcn_mfma_f32_16x16x32_bf16(a, b, c, 0, 0, 0)

// ---- bf16x3 split helpers: x = hi + lo (truncation split, exact subtraction) ----
struct FragPair { s16x8 hi, lo; };

__device__ __forceinline__ uint_t packhl(float x) {     // (hi bf16) | (lo bf16 << 16)
    uint_t b = __float_as_uint(x);
    uint_t hb = b & 0xffff0000u;
    float r = x - __uint_as_float(hb);
    return (b >> 16) | (__float_as_uint(r) & 0xffff0000u);
}
__device__ __forceinline__ FragPair split8v(const float x[8]) {
    uint_t h[4], l[4];
#pragma unroll
    for (int i = 0; i < 4; ++i) {
        uint_t b0 = __float_as_uint(x[2 * i]), b1 = __float_as_uint(x[2 * i + 1]);
        uint_t h0 = b0 & 0xffff0000u, h1 = b1 & 0xffff0000u;
        h[i] = (b0 >> 16) | h1;
        float r0 = x[2 * i] - __uint_as_float(h0);
        float r1 = x[2 * i + 1] - __uint_as_float(h1);
        l[i] = (__float_as_uint(r0) >> 16) | (__float_as_uint(r1) & 0xffff0000u);
    }
    FragPair f;
    f.hi = __builtin_bit_cast(s16x8, make_uint4(h[0], h[1], h[2], h[3]));
    f.lo = __builtin_bit_cast(s16x8, make_uint4(l[0], l[1], l[2], l[3]));
    return f;
}
__device__ __forceinline__ FragPair split8p(const float* p) {
    float x[8];
    float4 f0 = *(const float4*)p, f1 = *(const float4*)(p + 4);
    x[0] = f0.x; x[1] = f0.y; x[2] = f0.z; x[3] = f0.w;
    x[4] = f1.x; x[5] = f1.y; x[6] = f1.z; x[7] = f1.w;
    return split8v(x);
}
__device__ __forceinline__ FragPair unpack8(const uint_t* p) {
    uint4 a = *(const uint4*)p, b = *(const uint4*)(p + 4);
    uint_t h0 = (a.x & 0xffffu) | (a.y << 16);
    uint_t h1 = (a.z & 0xffffu) | (a.w << 16);
    uint_t h2 = (b.x & 0xffffu) | (b.y << 16);
    uint_t h3 = (b.z & 0xffffu) | (b.w << 16);
    uint_t l0 = (a.x >> 16) | (a.y & 0xffff0000u);
    uint_t l1 = (a.z >> 16) | (a.w & 0xffff0000u);
    uint_t l2 = (b.x >> 16) | (b.y & 0xffff0000u);
    uint_t l3 = (b.z >> 16) | (b.w & 0xffff0000u);
    FragPair f;
    f.hi = __builtin_bit_cast(s16x8, make_uint4(h0, h1, h2, h3));
    f.lo = __builtin_bit_cast(s16x8, make_uint4(l0, l1, l2, l3));
    return f;
}

// ---------------- 1. landmark means (Q_lm, K_lm), scale+mask folded ----------------
__global__ void lm_kernel(const float* __restrict__ Q, const float* __restrict__ K,
                          const float* __restrict__ M,
                          float* __restrict__ Qlm, float* __restrict__ Klm,
                          uint_t* __restrict__ scal) {
    int bhl = blockIdx.x;            // bh*128 + l
    int bh  = bhl >> 7;
    int l   = bhl & 127;
    int b   = bh / NH;
    const float* src = blockIdx.y ? K : Q;
    float* dst = blockIdx.y ? Klm : Qlm;
    int d = threadIdx.x;             // 64 threads
    size_t base = ((size_t)bh * SQ + (size_t)l * SEG) * HD + d;
    int mbase = b * SQ + l * SEG;
    float acc = 0.f;
#pragma unroll 8
    for (int j = 0; j < SEG; ++j)
        acc += src[base + (size_t)j * HD] * M[mbase + j];
    dst[(size_t)bhl * HD + d] = acc * (SCALE / (float)SEG);
    if (bhl == 0 && blockIdx.y == 0 && d < 2) scal[d] = 0u;
}

// ---------------- 2. kernel_2 = softmax(Qlm @ Klm^T), plus row sums ----------------
__global__ void k2_kernel(const float* __restrict__ Qlm, const float* __restrict__ Klm,
                          float* __restrict__ K2, float* __restrict__ rowsum) {
    int bh = blockIdx.x >> 7;
    int c  = threadIdx.x;            // 128 threads = one column each
    __shared__ float q[HD];
    __shared__ float red[NL];
    if (c < HD) q[c] = Qlm[(size_t)blockIdx.x * HD + c];
    __syncthreads();
    const float* krow = Klm + ((size_t)bh * NL + c) * HD;
    float s = 0.f;
#pragma unroll 16
    for (int d = 0; d < HD; ++d) s += q[d] * krow[d];
    red[c] = s; __syncthreads();
    for (int st = 64; st > 0; st >>= 1) { if (c < st) red[c] = fmaxf(red[c], red[c + st]); __syncthreads(); }
    float mx = red[0]; __syncthreads();
    float e = __expf(s - mx);
    red[c] = e; __syncthreads();
    for (int st = 64; st > 0; st >>= 1) { if (c < st) red[c] += red[c + st]; __syncthreads(); }
    float inv = 1.f / red[0]; __syncthreads();
    float p = e * inv;
    K2[(size_t)blockIdx.x * NL + c] = p;
    red[c] = p; __syncthreads();
    for (int st = 64; st > 0; st >>= 1) { if (c < st) red[c] += red[c + st]; __syncthreads(); }
    if (c == 0) rowsum[blockIdx.x] = red[0];
}

// ---------------- 3. global max col-sum / row-sum -> init_scale ingredients ----------------
__global__ void colmax_kernel(const float* __restrict__ K2, const float* __restrict__ rowsum,
                              uint_t* __restrict__ scal) {
    int bh = blockIdx.x;
    int c  = threadIdx.x;            // 128
    __shared__ float red[NL];
    float cs = 0.f;
    for (int r = 0; r < NL; ++r) cs += K2[((size_t)bh * NL + r) * NL + c];
    red[c] = cs; __syncthreads();
    for (int st = 64; st > 0; st >>= 1) { if (c < st) red[c] = fmaxf(red[c], red[c + st]); __syncthreads(); }
    if (c == 0) atomicMax(&scal[0], __float_as_uint(red[0]));
    __syncthreads();
    float rs = rowsum[bh * NL + c];
    red[c] = rs; __syncthreads();
    for (int st = 64; st > 0; st >>= 1) { if (c < st) red[c] = fmaxf(red[c], red[c + st]); __syncthreads(); }
    if (c == 0) atomicMax(&scal[1], __float_as_uint(red[0]));
}

// ---------------- 4. fused Newton inverse, bf16x3 MFMA, one workgroup per bh ----------------
// Stage: C = A @ (beta*I - B). A read as fp32 (split on the fly); B read from a
// packed (hi|lo<<16) uint array in B-layout [n][k]. Writes optional fp32 C (x alphaf)
// and optional pack C' [n][m] = packhl(beta'*(m==n) - alphap*x).
__device__ __forceinline__ void nstage(const float* __restrict__ Afp, int amode, float ascale,
                                       const uint_t* __restrict__ Bp,
                                       float* __restrict__ Cfp, float alphaf,
                                       uint_t* __restrict__ Cpk, float beta, float alphap,
                                       int wave, int quad, int l16) {
    f32x4 acc[8];
#pragma unroll
    for (int nt = 0; nt < 8; ++nt) acc[nt] = (f32x4){0.f, 0.f, 0.f, 0.f};
    int R0 = wave * 16;
#pragma unroll
    for (int kt = 0; kt < 4; ++kt) {
        FragPair A;
        if (amode == 0) {
            A = split8p(Afp + (size_t)(R0 + l16) * NL + kt * 32 + quad * 8);
        } else {          // A[m][k] = ascale * Afp[k][m]  (transposed gather)
            float x[8];
#pragma unroll
            for (int j = 0; j < 8; ++j)
                x[j] = ascale * Afp[(size_t)(kt * 32 + quad * 8 + j) * NL + R0 + l16];
            A = split8v(x);
        }
#pragma unroll
        for (int nt = 0; nt < 8; ++nt) {
            FragPair B = unpack8(Bp + (size_t)(nt * 16 + l16) * NL + kt * 32 + quad * 8);
            acc[nt] = MFMA16(A.lo, B.hi, acc[nt]);
            acc[nt] = MFMA16(A.hi, B.lo, acc[nt]);
            acc[nt] = MFMA16(A.hi, B.hi, acc[nt]);
        }
    }
#pragma unroll
    for (int nt = 0; nt < 8; ++nt)
#pragma unroll
        for (int r = 0; r < 4; ++r) {
            int m = R0 + quad * 4 + r, n = nt * 16 + l16;
            float x = acc[nt][r];
            if (Cfp) Cfp[(size_t)m * NL + n] = alphaf * x;
            if (Cpk) Cpk[(size_t)n * NL + m] = packhl(beta * (float)(m == n) - alphap * x);
        }
}

__global__ __launch_bounds__(512) void newton_fused(const float* __restrict__ K2,
                                                    const uint_t* __restrict__ scal,
                                                    float* __restrict__ KVf,   // also final Vinv
                                                    float* __restrict__ Vf0, float* __restrict__ Vf1,
                                                    uint_t* __restrict__ VB0, uint_t* __restrict__ VB1,
                                                    uint_t* __restrict__ KVB, uint_t* __restrict__ T1B) {
    int bh = blockIdx.x;
    int tid = threadIdx.x;
    int wave = tid >> 6, lane = tid & 63, quad = lane >> 4, l16 = lane & 15;
    float s = 1.f / (__uint_as_float(scal[0]) * __uint_as_float(scal[1]));
    const float* K2b = K2 + (size_t)bh * NL * NL;
    float* KVb = KVf + (size_t)bh * NL * NL;
    float* V[2] = {Vf0 + (size_t)bh * NL * NL, Vf1 + (size_t)bh * NL * NL};
    uint_t* VBb[2] = {VB0 + (size_t)bh * NL * NL, VB1 + (size_t)bh * NL * NL};
    uint_t* KVBb = KVB + (size_t)bh * NL * NL;
    uint_t* T1Bb = T1B + (size_t)bh * NL * NL;
    // prologue: V0 B-pack = pack(s * K2) (row-major == B-layout of V0 = s*K2^T)
    for (int idx = tid; idx < NL * NL; idx += 512)
        VBb[0][idx] = packhl(s * K2b[idx]);
    __syncthreads();
#pragma unroll 1
    for (int it = 0; it < 6; ++it) {
        // KV = K2 @ Vc             -> KVf fp32, KVB = 7I - KV (pack)
        nstage(K2b, 0, 1.f, VBb[it & 1], KVb, 1.f, KVBb, 7.f, 1.f, wave, quad, l16);
        __syncthreads();
        // T1 = KV @ (7I-KV)        -> T1B = 15I - T1 (pack only)
        nstage(KVb, 0, 1.f, KVBb, nullptr, 0.f, T1Bb, 15.f, 1.f, wave, quad, l16);
        __syncthreads();
        // T2 = KV @ (15I-T1)       -> T2B (aliases KVB, dead) = 13I - T2 (pack only)
        nstage(KVb, 0, 1.f, T1Bb, nullptr, 0.f, KVBb, 13.f, 1.f, wave, quad, l16);
        __syncthreads();
        // Vn = 0.25 * Vc @ (13I-T2) -> fp32 (x0.25) + pack (0.25x) ; last iter: Vinv only
        if (it == 0) {
            nstage(K2b, 1, s, KVBb, V[1], 0.25f, VBb[1], 0.f, -0.25f, wave, quad, l16);
        } else if (it < 5) {
            nstage(V[it & 1], 0, 1.f, KVBb, V[(it + 1) & 1], 0.25f, VBb[(it + 1) & 1], 0.f, -0.25f, wave, quad, l16);
        } else {   // write Vinv into KVf (KV dead after stage3 of last iter)
            nstage(V[1], 0, 1.f, KVBb, KVb, 0.25f, nullptr, 0.f, 0.f, wave, quad, l16);
        }
        __syncthreads();
    }
}

// ---------------- 6a. k3v flash, bf16 MFMA, key-split partials ----------------
#define KT 64
#define KP 72
__global__ __launch_bounds__(256) void k3v_mfma(const float* __restrict__ K, const float* __restrict__ V,
                                                const float* __restrict__ M, const float* __restrict__ Qlm,
                                                float* __restrict__ Opart, float* __restrict__ Mpart,
                                                float* __restrict__ Lpart) {
    int bh = blockIdx.y, b = bh / NH, ck = blockIdx.x;
    int tid = threadIdx.x;
    int wave = tid >> 6, lane = tid & 63, quad = lane >> 4, l16 = lane & 15;
    __shared__ ushort_t Ksh[KT * KP];
    __shared__ ushort_t Vsh[HD * KP];
    __shared__ ushort_t Psh[4 * 32 * KP];
    __shared__ float msc[KT], mbias[KT];
    int R0 = wave * 32;
    s16x8 aq[2][2];
#pragma unroll
    for (int rt = 0; rt < 2; ++rt)
#pragma unroll
        for (int ks = 0; ks < 2; ++ks) {
            const float* qp = Qlm + ((size_t)bh * NL + R0 + rt * 16 + l16) * HD + ks * 32 + quad * 8;
            float4 q0 = *(const float4*)qp;
            float4 q1 = *(const float4*)(qp + 4);
            aq[rt][ks] = __builtin_bit_cast(s16x8,
                make_uint4(pack2(q0.x, q0.y), pack2(q0.z, q0.w), pack2(q1.x, q1.y), pack2(q1.z, q1.w)));
        }
    float m_run[2][4], l_run[2][4];
    f32x4 o[2][4];
#pragma unroll
    for (int rt = 0; rt < 2; ++rt)
#pragma unroll
        for (int r = 0; r < 4; ++r) { m_run[rt][r] = -1e30f; l_run[rt][r] = 0.f; }
#pragma unroll
    for (int rt = 0; rt < 2; ++rt)
#pragma unroll
        for (int dn = 0; dn < 4; ++dn) o[rt][dn] = (f32x4){0.f, 0.f, 0.f, 0.f};

    const float4* Kg = (const float4*)(K + ((size_t)bh * SQ + ck * 512) * HD);
    const float4* Vg = (const float4*)(V + ((size_t)bh * SQ + ck * 512) * HD);
    const float* Mg = M + b * SQ + ck * 512;

    for (int t = 0; t < 8; ++t) {
        __syncthreads();
#pragma unroll
        for (int rep = 0; rep < 4; ++rep) {
            int idx = rep * 256 + tid;
            int key = idx >> 4, d4 = (idx & 15) * 4;
            float4 x = Kg[t * 1024 + idx];
            *(uint2*)&Ksh[key * KP + d4] = make_uint2(pack2(x.x, x.y), pack2(x.z, x.w));
            float4 y = Vg[t * 1024 + idx];
            Vsh[(d4 + 0) * KP + key] = f2bf(y.x);
            Vsh[(d4 + 1) * KP + key] = f2bf(y.y);
            Vsh[(d4 + 2) * KP + key] = f2bf(y.z);
            Vsh[(d4 + 3) * KP + key] = f2bf(y.w);
        }
        if (tid < KT) {
            float mv = Mg[t * KT + tid];
            msc[tid] = mv * SCALE;
            mbias[tid] = -NEGBIG * (1.f - mv);
        }
        __syncthreads();
#pragma unroll
        for (int rt = 0; rt < 2; ++rt) {
            f32x4 acc[4];
#pragma unroll
            for (int nt = 0; nt < 4; ++nt) acc[nt] = (f32x4){0.f, 0.f, 0.f, 0.f};
#pragma unroll
            for (int nt = 0; nt < 4; ++nt)
#pragma unroll
                for (int ks = 0; ks < 2; ++ks) {
                    s16x8 bf = ld_frag(&Ksh[(nt * 16 + l16) * KP + ks * 32 + quad * 8]);
                    acc[nt] = MFMA16(aq[rt][ks], bf, acc[nt]);
                }
            float s[4][4];
#pragma unroll
            for (int nt = 0; nt < 4; ++nt) {
                float mm = msc[nt * 16 + l16], bb = mbias[nt * 16 + l16];
#pragma unroll
                for (int r = 0; r < 4; ++r) s[nt][r] = acc[nt][r] * mm + bb;
            }
            float mx[4];
#pragma unroll
            for (int r = 0; r < 4; ++r)
                mx[r] = fmaxf(fmaxf(s[0][r], s[1][r]), fmaxf(s[2][r], s[3][r]));
#pragma unroll
            for (int off = 1; off < 16; off <<= 1)
#pragma unroll
                for (int r = 0; r < 4; ++r) mx[r] = fmaxf(mx[r], __shfl_xor(mx[r], off));
            float al[4];
#pragma unroll
            for (int r = 0; r < 4; ++r) {
                float mn = fmaxf(m_run[rt][r], mx[r]);
                al[r] = __expf(m_run[rt][r] - mn);
                m_run[rt][r] = mn;
            }
            float ps[4] = {0.f, 0.f, 0.f, 0.f};
            int prow = wave * 32 + rt * 16;
#pragma unroll
            for (int nt = 0; nt < 4; ++nt)
#pragma unroll
                for (int r = 0; r < 4; ++r) {
                    float p = __expf(s[nt][r] - m_run[rt][r]);
                    ps[r] += p;
                    Psh[(prow + quad * 4 + r) * KP + nt * 16 + l16] = f2bf(p);
                }
#pragma unroll
            for (int off = 1; off < 16; off <<= 1)
#pragma unroll
                for (int r = 0; r < 4; ++r) ps[r] += __shfl_xor(ps[r], off);
#pragma unroll
            for (int r = 0; r < 4; ++r) l_run[rt][r] = l_run[rt][r] * al[r] + ps[r];
#pragma unroll
            for (int dn = 0; dn < 4; ++dn)
#pragma unroll
                for (int r = 0; r < 4; ++r) o[rt][dn][r] *= al[r];
#pragma unroll
            for (int dn = 0; dn < 4; ++dn)
#pragma unroll
                for (int ks = 0; ks < 2; ++ks) {
                    s16x8 af = ld_frag(&Psh[(prow + l16) * KP + ks * 32 + quad * 8]);
                    s16x8 bf = ld_frag(&Vsh[(dn * 16 + l16) * KP + ks * 32 + quad * 8]);
                    o[rt][dn] = MFMA16(af, bf, o[rt][dn]);
                }
        }
    }
    size_t pbase = ((size_t)bh * 8 + ck) * NL;
#pragma unroll
    for (int rt = 0; rt < 2; ++rt)
#pragma unroll
        for (int dn = 0; dn < 4; ++dn)
#pragma unroll
            for (int r = 0; r < 4; ++r) {
                int row = R0 + rt * 16 + quad * 4 + r;
                Opart[(pbase + row) * HD + dn * 16 + l16] = o[rt][dn][r];
            }
    if (l16 == 0) {
#pragma unroll
        for (int rt = 0; rt < 2; ++rt)
#pragma unroll
            for (int r = 0; r < 4; ++r) {
                int row = R0 + rt * 16 + quad * 4 + r;
                Mpart[pbase + row] = m_run[rt][r];
                Lpart[pbase + row] = l_run[rt][r];
            }
    }
}

// ---------------- 6b. combine key-split partials -> A ----------------
__global__ __launch_bounds__(256) void k3c_kernel(const float* __restrict__ Opart,
                                                  const float* __restrict__ Mpart,
                                                  const float* __restrict__ Lpart,
                                                  float* __restrict__ A) {
    int bh = blockIdx.y;
    int tid = threadIdx.x;
    int r = blockIdx.x * 64 + (tid >> 2);
    int dg = (tid & 3) * 16;
    size_t base = (size_t)bh * 8 * NL;
    float m[8], Mx = -1e30f;
#pragma unroll
    for (int ck = 0; ck < 8; ++ck) { m[ck] = Mpart[base + ck * NL + r]; Mx = fmaxf(Mx, m[ck]); }
    float w[8], l = 0.f;
#pragma unroll
    for (int ck = 0; ck < 8; ++ck) { w[ck] = __expf(m[ck] - Mx); l += w[ck] * Lpart[base + ck * NL + r]; }
    float inv = 1.f / l;
#pragma unroll
    for (int d4 = 0; d4 < 16; d4 += 4) {
        float4 acc = make_float4(0.f, 0.f, 0.f, 0.f);
#pragma unroll
        for (int ck = 0; ck < 8; ++ck) {
            float4 v = *(const float4*)&Opart[(base + ck * NL + r) * HD + dg + d4];
            acc.x += w[ck] * v.x; acc.y += w[ck] * v.y; acc.z += w[ck] * v.z; acc.w += w[ck] * v.w;
        }
        acc.x *= inv; acc.y *= inv; acc.z *= inv; acc.w *= inv;
        *(float4*)&A[((size_t)bh * NL + r) * HD + dg + d4] = acc;
    }
}

// ---------------- 7. W = Vinv @ A ----------------
__global__ __launch_bounds__(256) void w_kernel(const float* __restrict__ Vinv, const float* __restrict__ A,
                                                float* __restrict__ W) {
    int bh = blockIdx.y;
    int r0 = blockIdx.x * 32;
    __shared__ float Ash[128][64];
    __shared__ float Vl[32][129];
    int tid = threadIdx.x;
    for (int idx = tid; idx < 8192; idx += 256) Ash[idx >> 6][idx & 63] = A[(size_t)bh * 8192 + idx];
    for (int idx = tid; idx < 4096; idx += 256) {
        int r = idx >> 7, k = idx & 127;
        Vl[r][k] = Vinv[(size_t)bh * 16384 + (size_t)(r0 + r) * NL + k];
    }
    __syncthreads();
    int d = tid & 63, rg = tid >> 6;
    float acc[8] = {};
    for (int k = 0; k < NL; ++k) {
        float av = Ash[k][d];
#pragma unroll
        for (int i = 0; i < 8; ++i) acc[i] += Vl[rg * 8 + i][k] * av;
    }
#pragma unroll
    for (int i = 0; i < 8; ++i)
        W[(size_t)bh * 8192 + (size_t)(r0 + rg * 8 + i) * HD + d] = acc[i];
}

// ---------------- 8. X = softmax(Qs @ Klm^T) @ W, bf16 MFMA ----------------
#define QP 72
#define WP 136
__global__ __launch_bounds__(256) void k1x_mfma(const float* __restrict__ Q, const float* __restrict__ M,
                                                const float* __restrict__ Klm, const float* __restrict__ W,
                                                float* __restrict__ out) {
    int bh = blockIdx.y, b = bh / NH, q0 = blockIdx.x * 64;
    int tid = threadIdx.x;
    int wave = tid >> 6, lane = tid & 63, quad = lane >> 4, l16 = lane & 15;
    __shared__ ushort_t Qsh[64 * QP];
    __shared__ ushort_t Bsh[128 * QP];
    __shared__ ushort_t Wt[64 * WP];
    const float4* Qg = (const float4*)(Q + ((size_t)bh * SQ + q0) * HD);
#pragma unroll
    for (int rep = 0; rep < 4; ++rep) {
        int idx = rep * 256 + tid;
        int r = idx >> 4, d4 = (idx & 15) * 4;
        float4 x = Qg[idx];
        float mm = M[b * SQ + q0 + r] * SCALE;
        *(uint2*)&Qsh[r * QP + d4] = make_uint2(pack2(x.x * mm, x.y * mm), pack2(x.z * mm, x.w * mm));
    }
    const float4* Kg = (const float4*)(Klm + (size_t)bh * NL * HD);
#pragma unroll
    for (int rep = 0; rep < 8; ++rep) {
        int idx = rep * 256 + tid;
        int r = idx >> 4, d4 = (idx & 15) * 4;
        float4 x = Kg[idx];
        *(uint2*)&Bsh[r * QP + d4] = make_uint2(pack2(x.x, x.y), pack2(x.z, x.w));
    }
    const float4* Wg = (const float4*)(W + (size_t)bh * NL * HD);
#pragma unroll
    for (int rep = 0; rep < 8; ++rep) {
        int idx = rep * 256 + tid;
        int lm = idx >> 4, d4 = (idx & 15) * 4;
        float4 x = Wg[idx];
        Wt[(d4 + 0) * WP + lm] = f2bf(x.x);
        Wt[(d4 + 1) * WP + lm] = f2bf(x.y);
        Wt[(d4 + 2) * WP + lm] = f2bf(x.z);
        Wt[(d4 + 3) * WP + lm] = f2bf(x.w);
    }
    __syncthreads();
    int R = wave * 16;
    s16x8 aq[2];
#pragma unroll
    for (int ks = 0; ks < 2; ++ks) aq[ks] = ld_frag(&Qsh[(R + l16) * QP + ks * 32 + quad * 8]);
    f32x4 acc[8];
#pragma unroll
    for (int nt = 0; nt < 8; ++nt) acc[nt] = (f32x4){0.f, 0.f, 0.f, 0.f};
#pragma unroll
    for (int nt = 0; nt < 8; ++nt)
#pragma unroll
        for (int ks = 0; ks < 2; ++ks) {
            s16x8 bf = ld_frag(&Bsh[(nt * 16 + l16) * QP + ks * 32 + quad * 8]);
            acc[nt] = MFMA16(aq[ks], bf, acc[nt]);
        }
    float mx[4];
#pragma unroll
    for (int r = 0; r < 4; ++r) {
        mx[r] = acc[0][r];
#pragma unroll
        for (int nt = 1; nt < 8; ++nt) mx[r] = fmaxf(mx[r], acc[nt][r]);
    }
#pragma unroll
    for (int off = 1; off < 16; off <<= 1)
#pragma unroll
        for (int r = 0; r < 4; ++r) mx[r] = fmaxf(mx[r], __shfl_xor(mx[r], off));
    float ps[4] = {0.f, 0.f, 0.f, 0.f};
#pragma unroll
    for (int nt = 0; nt < 8; ++nt)
#pragma unroll
        for (int r = 0; r < 4; ++r) {
            float p = __expf(acc[nt][r] - mx[r]);
            acc[nt][r] = p;
            ps[r] += p;
        }
#pragma unroll
    for (int off = 1; off < 16; off <<= 1)
#pragma unroll
        for (int r = 0; r < 4; ++r) ps[r] += __shfl_xor(ps[r], off);
    float inv[4];
#pragma unroll
    for (int r = 0; r < 4; ++r) inv[r] = 1.f / ps[r];
    __syncthreads();
    ushort_t* Psh = Bsh;
#pragma unroll
    for (int nt = 0; nt < 8; ++nt)
#pragma unroll
        for (int r = 0; r < 4; ++r)
            Psh[(R + quad * 4 + r) * WP + nt * 16 + l16] = f2bf(acc[nt][r] * inv[r]);
    f32x4 o[4];
#pragma unroll
    for (int dn = 0; dn < 4; ++dn) o[dn] = (f32x4){0.f, 0.f, 0.f, 0.f};
#pragma unroll
    for (int dn = 0; dn < 4; ++dn)
#pragma unroll
        for (int ks = 0; ks < 4; ++ks) {
            s16x8 af = ld_frag(&Psh[(R + l16) * WP + ks * 32 + quad * 8]);
            s16x8 bf = ld_frag(&Wt[(dn * 16 + l16) * WP + ks * 32 + quad * 8]);
            o[dn] = MFMA16(af, bf, o[dn]);
        }
    float* op = out + ((size_t)bh * SQ + q0) * HD;
#pragma unroll
    for (int dn = 0; dn < 4; ++dn)
#pragma unroll
        for (int r = 0; r < 4; ++r)
            op[(R + quad * 4 + r) * HD + dn * 16 + l16] = o[dn][r];
}

extern "C" void kernel_launch(void* const* d_in, const int* in_sizes, int n_in,
                              void* d_out, int out_size, void* d_ws, size_t ws_size,
                              hipStream_t stream) {
    const float* Q = (const float*)d_in[0];
    const float* K = (const float*)d_in[1];
    const float* V = (const float*)d_in[2];
    const float* M = (const float*)d_in[3];
    float* out = (float*)d_out;

    float* ws  = (float*)d_ws;
    // fp32 region
    float* Qlm = ws;                       // 393216
    float* Klm = Qlm + 393216;             // 393216
    float* K2  = Klm + 393216;             // 786432  (Ab aliases after newton)
    float* KVf = K2  + 786432;             // 786432  (Vinv lands here)
    float* Vf0 = KVf + 786432;             // 786432  (Wb aliases after newton)
    float* Vf1 = Vf0 + 786432;             // 786432  (Mpart/Lpart alias after newton)
    // packed bf16x2 region (dead after newton; Opart aliases all 4)
    uint_t* VB0 = (uint_t*)(Vf1 + 786432); // 786432 u
    uint_t* VB1 = VB0 + 786432;
    uint_t* KVB = VB1 + 786432;
    uint_t* T1B = KVB + 786432;
    float* rowsum = (float*)(T1B + 786432);// 6144
    uint_t* scal  = (uint_t*)(rowsum + 6144); // 16
    // post-newton aliases
    float* Vinv  = KVf;
    float* Opart = (float*)VB0;            // 3145728 floats = 4 pack buffers exactly
    float* Ab    = K2;                     // 393216 (fits in K2's 786432)
    float* Wb    = Vf0;                    // 393216
    float* Mpart = Vf1;                    // 49152
    float* Lpart = Vf1 + 49152;            // 49152

    lm_kernel<<<dim3(6144, 2), 64, 0, stream>>>(Q, K, M, Qlm, Klm, scal);
    k2_kernel<<<6144, 128, 0, stream>>>(Qlm, Klm, K2, rowsum);
    colmax_kernel<<<48, 128, 0, stream>>>(K2, rowsum, scal);
    newton_fused<<<48, 512, 0, stream>>>(K2, scal, KVf, Vf0, Vf1, VB0, VB1, KVB, T1B);

    k3v_mfma<<<dim3(8, 48), 256, 0, stream>>>(K, V, M, Qlm, Opart, Mpart, Lpart);
    k3c_kernel<<<dim3(2, 48), 256, 0, stream>>>(Opart, Mpart, Lpart, Ab);
    w_kernel<<<dim3(4, 48), 256, 0, stream>>>(Vinv, Ab, Wb);
    k1x_mfma<<<dim3(64, 48), 256, 0, stream>>>(Q, M, Klm, Wb, out);
}